// Round 7
// baseline (270.795 us; speedup 1.0000x reference)
//
#include <hip/hip_runtime.h>
#include <hip/hip_bf16.h>
#include <hip/hip_fp16.h>

// ==================== counting-sort CSR build (no device atomics) ====================
constexpr int G1 = 96;         // edge-chunk blocks
constexpr int RNODES = 12544;  // nodes per LDS range

// K1: per-(chunk, range) histogram via LDS packed-u16 atomics. grid = (G1, ranges)
__global__ __launch_bounds__(256) void histo_kernel(const int* __restrict__ dst,
                                                    unsigned short* __restrict__ hist,
                                                    int E, int chunk, int npad2) {
    __shared__ unsigned int h32[RNODES / 2];
    int g = blockIdx.x;
    int base = blockIdx.y * RNODES;
    int e0 = g * chunk;
    int e1 = min(e0 + chunk, E);
    for (int i = threadIdx.x; i < RNODES / 2; i += 256) h32[i] = 0;
    __syncthreads();
    for (int e = e0 + threadIdx.x; e < e1; e += 256) {
        int d = dst[e] - base;
        if (d >= 0 && d < RNODES) atomicAdd(&h32[d >> 1], 1u << ((d & 1) * 16));
    }
    __syncthreads();
    for (int i = threadIdx.x; i < RNODES; i += 256) {
        unsigned int v = (h32[i >> 1] >> ((i & 1) * 16)) & 0xFFFFu;
        hist[(size_t)g * npad2 + base + i] = (unsigned short)v;
    }
}

// K2 (fused): cnt + dis + off16 (per-chunk u16 prefix) + per-block partial sums.
// block = 1024 nodes, thread = 4 consecutive nodes.
__global__ __launch_bounds__(256) void scanA_kernel(const unsigned short* __restrict__ hist,
                                                    int* __restrict__ cnt, float* __restrict__ dis,
                                                    unsigned short* __restrict__ off16,
                                                    int* __restrict__ partial, int N, int npad2) {
    __shared__ int s[256];
    int t = threadIdx.x;
    int base = blockIdx.x * 1024 + t * 4;
    int acc[4] = {0, 0, 0, 0};
    for (int g = 0; g < G1; ++g) {
        const unsigned short* hp = hist + (size_t)g * npad2;
        unsigned short* op = off16 + (size_t)g * npad2;
#pragma unroll
        for (int k = 0; k < 4; ++k) {
            int idx = base + k;
            if (idx < N) {
                op[idx] = (unsigned short)acc[k];
                acc[k] += hp[idx];
            }
        }
    }
    int tot = 0;
#pragma unroll
    for (int k = 0; k < 4; ++k) {
        int idx = base + k;
        if (idx < N) {
            cnt[idx] = acc[k];
            dis[idx] = rsqrtf((float)acc[k] + 1.0f);
            tot += acc[k];
        }
    }
    s[t] = tot;
    __syncthreads();
    for (int off = 128; off > 0; off >>= 1) {
        if (t < off) s[t] += s[t + off];
        __syncthreads();
    }
    if (t == 0) partial[blockIdx.x] = s[0];
}

__global__ __launch_bounds__(64) void scan_partials(int* __restrict__ partial, int G) {
    int t = threadIdx.x;
    int o = (t < G) ? partial[t] : 0;
    int v = o;
#pragma unroll
    for (int off = 1; off < 64; off <<= 1) {
        int u = __shfl_up(v, off, 64);
        if (t >= off) v += u;
    }
    if (t < G) partial[t] = v - o;
}

__global__ __launch_bounds__(256) void scan_write(const int* __restrict__ cnt,
                                                  const int* __restrict__ partial,
                                                  int* __restrict__ cursor, int N) {
    __shared__ int s[256];
    int t = threadIdx.x;
    int base = blockIdx.x * 1024 + t * 4;
    int loc[4];
    int v = 0;
#pragma unroll
    for (int k = 0; k < 4; ++k) {
        int idx = base + k;
        loc[k] = (idx < N) ? cnt[idx] : 0;
        v += loc[k];
    }
    s[t] = v;
    __syncthreads();
    for (int off = 1; off < 256; off <<= 1) {
        int add = (t >= off) ? s[t - off] : 0;
        __syncthreads();
        s[t] += add;
        __syncthreads();
    }
    int run = partial[blockIdx.x] + s[t] - v;
#pragma unroll
    for (int k = 0; k < 4; ++k) {
        int idx = base + k;
        if (idx < N) {
            cursor[idx] = run;
            run += loc[k];
        }
    }
}

__global__ __launch_bounds__(1024) void scan_kernel(const int* __restrict__ cnt,
                                                    int* __restrict__ cursor, int N) {
    constexpr int T = 1024;
    __shared__ int sums[T];
    int t = threadIdx.x;
    int ch = (N + T - 1) / T;
    int base = t * ch;
    int local = 0;
    for (int k = 0; k < ch; ++k) {
        int idx = base + k;
        if (idx < N) local += cnt[idx];
    }
    sums[t] = local;
    __syncthreads();
    for (int off = 1; off < T; off <<= 1) {
        int add = (t >= off) ? sums[t - off] : 0;
        __syncthreads();
        sums[t] += add;
        __syncthreads();
    }
    int run = sums[t] - local;
    for (int k = 0; k < ch; ++k) {
        int idx = base + k;
        if (idx < N) {
            cursor[idx] = run;
            run += cnt[idx];
        }
    }
}

// K4: fill csr_src — u32 LDS counters preloaded with cursor+off16 give global pos directly.
__global__ __launch_bounds__(256) void fill2_kernel(const int* __restrict__ src,
                                                    const int* __restrict__ dst,
                                                    const int* __restrict__ cursor,
                                                    const unsigned short* __restrict__ off16,
                                                    int* __restrict__ csr_src,
                                                    int E, int chunk, int npad2) {
    __shared__ unsigned int c[RNODES];
    int g = blockIdx.x;
    int base = blockIdx.y * RNODES;
    for (int i = threadIdx.x; i < RNODES; i += 256)
        c[i] = (unsigned int)cursor[base + i] + (unsigned int)off16[(size_t)g * npad2 + base + i];
    __syncthreads();
    int e0 = g * chunk;
    int e1 = min(e0 + chunk, E);
    for (int e = e0 + threadIdx.x; e < e1; e += 256) {
        int d = dst[e] - base;
        if (d >= 0 && d < RNODES) {
            unsigned int pos = atomicAdd(&c[d], 1u);
            csr_src[pos] = src[e];
        }
    }
}

// ==================== fallback CSR build (device atomics) ====================
__global__ void degree_int_kernel(const int* __restrict__ dst, int* __restrict__ cnt, int E) {
    int i = blockIdx.x * blockDim.x + threadIdx.x;
    if (i < E) atomicAdd(&cnt[dst[i]], 1);
}

__global__ void dis_from_cnt_kernel(const int* __restrict__ cnt, float* __restrict__ dis, int N) {
    int i = blockIdx.x * blockDim.x + threadIdx.x;
    if (i < N) dis[i] = rsqrtf((float)cnt[i] + 1.0f);
}

__global__ void zero_int_kernel(int* __restrict__ p, int N) {
    int i = blockIdx.x * blockDim.x + threadIdx.x;
    if (i < N) p[i] = 0;
}

__global__ void fill_atomic_kernel(const int* __restrict__ src, const int* __restrict__ dst,
                                   int* __restrict__ cursor_mut, int* __restrict__ csr_src,
                                   int E) {
    int e = blockIdx.x * blockDim.x + threadIdx.x;
    if (e >= E) return;
    int pos = atomicAdd(&cursor_mut[dst[e]], 1);
    csr_src[pos] = src[e];
}

// ==================== cast+scale: Th[n][j] = half(x[n][j] * dis[n]) ====================
__global__ void cast_scale_kernel(const float* __restrict__ X, const float* __restrict__ dis,
                                  __half* __restrict__ Th, int N) {
    int i = blockIdx.x * blockDim.x + threadIdx.x;
    int n = i >> 3;
    if (n >= N) return;
    int c = (i & 7) * 8;
    float dn = dis[n];
    float4 a = *(const float4*)(X + (size_t)n * 64 + c);
    float4 b = *(const float4*)(X + (size_t)n * 64 + c + 4);
    __half2 h[4];
    h[0] = __floats2half2_rn(a.x * dn, a.y * dn);
    h[1] = __floats2half2_rn(a.z * dn, a.w * dn);
    h[2] = __floats2half2_rn(b.x * dn, b.y * dn);
    h[3] = __floats2half2_rn(b.z * dn, b.w * dn);
    *(float4*)(Th + (size_t)n * 64 + c) = *(float4*)h;
}

// ==================== tiled GEMM v2: k-unroll-4, float4 LDS X reads ====================
// out fp32 (+bias+relu) or fp16 scaled by dis (layer-2 gather table).
template <int K, int F, int RF, bool BIAS_RELU, bool OUT_HALF>
__global__ __launch_bounds__(256) void gemm_tiled(const float* __restrict__ X,
                                                  const float* __restrict__ W,
                                                  const float* __restrict__ bias,
                                                  const float* __restrict__ disscale,
                                                  void* __restrict__ outv, int N) {
    constexpr int TM = 64, RN = 4, XS = K + 4;
    static_assert(F == 16 * RF, "");
    __shared__ float Xs[TM * XS];
    __shared__ float Ws[K * F];

    const int n0 = blockIdx.x * TM;
    const int t = threadIdx.x;

    for (int i = t; i < (K * F) / 4; i += 256)
        ((float4*)Ws)[i] = ((const float4*)W)[i];
    for (int i = t; i < (TM * K) / 4; i += 256) {
        int row = i / (K / 4);
        int c4 = (i - row * (K / 4)) * 4;
        float4 v = make_float4(0.f, 0.f, 0.f, 0.f);
        if (n0 + row < N) v = *(const float4*)(X + (size_t)(n0 + row) * K + c4);
        *(float4*)(Xs + row * XS + c4) = v;
    }
    __syncthreads();

    const int tn = t >> 4;
    const int tf = t & 15;
    float acc[RN][RF] = {};
    for (int k0 = 0; k0 < K; k0 += 4) {
        float4 xv[RN];
#pragma unroll
        for (int i = 0; i < RN; ++i)
            xv[i] = *(const float4*)(Xs + (tn * RN + i) * XS + k0);
        float wv[4][RF];
#pragma unroll
        for (int j4 = 0; j4 < 4; ++j4)
#pragma unroll
            for (int j = 0; j < RF / 2; ++j) {
                float2 w2 = *(const float2*)(Ws + (k0 + j4) * F + tf * RF + 2 * j);
                wv[j4][2 * j] = w2.x;
                wv[j4][2 * j + 1] = w2.y;
            }
#pragma unroll
        for (int i = 0; i < RN; ++i) {
            const float xk[4] = {xv[i].x, xv[i].y, xv[i].z, xv[i].w};
#pragma unroll
            for (int j4 = 0; j4 < 4; ++j4)
#pragma unroll
                for (int j = 0; j < RF; ++j) acc[i][j] += xk[j4] * wv[j4][j];
        }
    }

    float breg[RF];
    if (BIAS_RELU) {
#pragma unroll
        for (int j = 0; j < RF; ++j) breg[j] = bias[tf * RF + j];
    }
#pragma unroll
    for (int i = 0; i < RN; ++i) {
        int n = n0 + tn * RN + i;
        if (n < N) {
            float v[RF];
#pragma unroll
            for (int j = 0; j < RF; ++j) {
                v[j] = acc[i][j];
                if (BIAS_RELU) v[j] = fmaxf(v[j] + breg[j], 0.f);
            }
            if (OUT_HALF) {
                float dn = disscale[n];
                __half* op = (__half*)outv + (size_t)n * F + tf * RF;
#pragma unroll
                for (int j = 0; j < RF / 2; ++j)
                    *(__half2*)(op + 2 * j) =
                        __floats2half2_rn(v[2 * j] * dn, v[2 * j + 1] * dn);
            } else {
                float* op = (float*)outv + (size_t)n * F + tf * RF;
#pragma unroll
                for (int j = 0; j < RF; ++j) op[j] = v[j];
            }
        }
    }
}

// ==================== CSR gather-aggregate, pre-scaled fp16 table ====================
// table rows are already scaled by dis[src]; result = dn * (sum + self-row).
// MODE 0: out = dn*S                       MODE 1: out = sigmoid(dn*S + b)
template <int MODE>
__global__ __launch_bounds__(256) void agg64h_kernel(const int* __restrict__ cursor,
                                                     const int* __restrict__ cnt,
                                                     const int* __restrict__ csr_src,
                                                     const float* __restrict__ dis,
                                                     const __half* __restrict__ Xh,
                                                     const float* __restrict__ b,
                                                     float* __restrict__ out, int N) {
    int i = blockIdx.x * 256 + threadIdx.x;
    int n = i >> 3;
    if (n >= N) return;
    int c = (i & 7) * 8;
    int beg = cursor[n];
    int end = beg + cnt[n];
    float a[8] = {};
    for (int j = beg; j < end; ++j) {
        int s = csr_src[j];
        float4 raw = *(const float4*)(Xh + (size_t)s * 64 + c);
        const __half2* hp = (const __half2*)&raw;
#pragma unroll
        for (int q = 0; q < 4; ++q) {
            float2 f = __half22float2(hp[q]);
            a[2 * q] += f.x;
            a[2 * q + 1] += f.y;
        }
    }
    {  // self row (also pre-scaled by dis[n])
        float4 raw = *(const float4*)(Xh + (size_t)n * 64 + c);
        const __half2* hp = (const __half2*)&raw;
#pragma unroll
        for (int q = 0; q < 4; ++q) {
            float2 f = __half22float2(hp[q]);
            a[2 * q] += f.x;
            a[2 * q + 1] += f.y;
        }
    }
    float dn = dis[n];
    float r[8];
#pragma unroll
    for (int q = 0; q < 8; ++q) r[q] = a[q] * dn;
    if (MODE == 1) {
#pragma unroll
        for (int q = 0; q < 8; ++q) r[q] = 1.f / (1.f + expf(-(r[q] + b[c + q])));
    }
    *(float4*)(out + (size_t)n * 64 + c) = make_float4(r[0], r[1], r[2], r[3]);
    *(float4*)(out + (size_t)n * 64 + c + 4) = make_float4(r[4], r[5], r[6], r[7]);
}

// ============================ launch ============================
extern "C" void kernel_launch(void* const* d_in, const int* in_sizes, int n_in,
                              void* d_out, int out_size, void* d_ws, size_t ws_size,
                              hipStream_t stream) {
    const float* x  = (const float*)d_in[0];
    const int*   ei = (const int*)d_in[1];
    const float* W1 = (const float*)d_in[2];
    const float* b1 = (const float*)d_in[3];
    const float* W2 = (const float*)d_in[4];
    const float* b2 = (const float*)d_in[5];

    constexpr int LAT = 64, HID = 96, OUTF = 64;
    const int E = in_sizes[1] / 2;
    const int N = in_sizes[0] / LAT;
    const int* src = ei;
    const int* dst = ei + E;

    const int B = 256;
    auto blocks = [](long total, int b) { return (int)((total + b - 1) / b); };

    const int ranges = (N + RNODES - 1) / RNODES;
    const int npad2 = ranges * RNODES;
    const int chunk = (E + G1 - 1) / G1;

    // ---- workspace layout (node arrays sized to cover both N-pad and npad2)
    long nmax = (npad2 > N) ? npad2 : N;
    size_t Na = (size_t)((nmax + 1023) / 1024) * 1024;
    size_t Epad = (size_t)((E + 3) / 4) * 4;
    int* cnt     = (int*)d_ws;               // Na
    int* cursor  = cnt + Na;                 // Na
    int* cursmut = cursor + Na;              // Na (fallback only)
    float* dis   = (float*)(cursmut + Na);   // Na
    int* partial = (int*)(dis + Na);         // 1024
    int* csr_src = partial + 1024;           // Epad
    char* region = (char*)(csr_src + Epad);
    // region phase A (build): hist u16 [G1*npad2] + off16 u16 [G1*npad2]
    unsigned short* hist  = (unsigned short*)region;
    unsigned short* off16 = hist + (size_t)G1 * npad2;
    // region phase B: Y fp32 [N*64] | H1 fp32 [N*96]; fp16 tables alias dead fp32 space
    float*  Y  = (float*)region;
    float*  H1 = Y + (size_t)N * 64;
    __half* Th = (__half*)H1;  // layer-1 table (dead before H1 written)

    size_t fixed = (4 * Na + 1024 + Epad) * sizeof(int);
    size_t regionA = (size_t)G1 * npad2 * 2 * sizeof(unsigned short);
    size_t regionB = ((size_t)N * 64 + (size_t)N * HID) * sizeof(float);
    size_t need = fixed + (regionA > regionB ? regionA : regionB);

    int Gn = blocks(N, 1024);
    bool fast = (ws_size >= need) && (chunk < 65536) && (ranges <= 8) && (Gn <= 64);

    if (fast) {
        dim3 g2(G1, ranges);
        histo_kernel<<<g2, 256, 0, stream>>>(dst, hist, E, chunk, npad2);
        scanA_kernel<<<Gn, 256, 0, stream>>>(hist, cnt, dis, off16, partial, N, npad2);
        scan_partials<<<1, 64, 0, stream>>>(partial, Gn);
        scan_write<<<Gn, 256, 0, stream>>>(cnt, partial, cursor, N);
        fill2_kernel<<<g2, 256, 0, stream>>>(src, dst, cursor, off16, csr_src, E, chunk, npad2);
    } else {
        // fallback: device-atomic CSR build
        zero_int_kernel<<<blocks(N, B), B, 0, stream>>>(cnt, N);
        degree_int_kernel<<<blocks(E, B), B, 0, stream>>>(dst, cnt, E);
        dis_from_cnt_kernel<<<blocks(N, B), B, 0, stream>>>(cnt, dis, N);
        if (Gn <= 64) {
            // reuse multi-block scan (scanA not needed; do sums via scan_write path)
            scan_kernel<<<1, 1024, 0, stream>>>(cnt, cursor, N);
        } else {
            scan_kernel<<<1, 1024, 0, stream>>>(cnt, cursor, N);
        }
        hipMemcpyAsync(cursmut, cursor, (size_t)N * sizeof(int), hipMemcpyDeviceToDevice, stream);
        fill_atomic_kernel<<<blocks(E, B), B, 0, stream>>>(src, dst, cursmut, csr_src, E);
    }

    // ---- layer 1: Th = half(x*dis); Y = dn*(sum Th); H1 = relu(Y@W1 + b1)
    cast_scale_kernel<<<blocks((long)N * 8, B), B, 0, stream>>>(x, dis, Th, N);
    agg64h_kernel<0><<<blocks((long)N * 8, B), B, 0, stream>>>(cursor, cnt, csr_src, dis, Th,
                                                               nullptr, Y, N);
    gemm_tiled<LAT, HID, 6, true, false>
        <<<blocks(N, 64), 256, 0, stream>>>(Y, W1, b1, nullptr, H1, N);

    // ---- layer 2: Th2 = half((H1@W2)*dis) (aliases Y); out = sigmoid(dn*sum + b2)
    gemm_tiled<HID, OUTF, 4, false, true>
        <<<blocks(N, 64), 256, 0, stream>>>(H1, W2, nullptr, dis, (void*)Y, N);
    agg64h_kernel<1><<<blocks((long)N * 8, B), B, 0, stream>>>(cursor, cnt, csr_src, dis,
                                                               (const __half*)Y, b2,
                                                               (float*)d_out, N);
}

// Round 8
// 213.791 us; speedup vs baseline: 1.2666x; 1.2666x over previous
//
#include <hip/hip_runtime.h>
#include <hip/hip_bf16.h>
#include <hip/hip_fp16.h>

// ==================== counting-sort CSR build (no device atomics) ====================
constexpr int G1 = 96;         // edge-chunk blocks
constexpr int RNODES = 12544;  // nodes per LDS range

// K1: per-(chunk, range) histogram via LDS packed-u16 atomics. grid = (G1, ranges)
__global__ __launch_bounds__(256) void histo_kernel(const int* __restrict__ dst,
                                                    unsigned short* __restrict__ hist,
                                                    int E, int chunk, int npad2) {
    __shared__ unsigned int h32[RNODES / 2];
    int g = blockIdx.x;
    int base = blockIdx.y * RNODES;
    int e0 = g * chunk;
    int e1 = min(e0 + chunk, E);
    for (int i = threadIdx.x; i < RNODES / 2; i += 256) h32[i] = 0;
    __syncthreads();
    for (int e = e0 + threadIdx.x; e < e1; e += 256) {
        int d = dst[e] - base;
        if (d >= 0 && d < RNODES) atomicAdd(&h32[d >> 1], 1u << ((d & 1) * 16));
    }
    __syncthreads();
    for (int i = threadIdx.x; i < RNODES; i += 256) {
        unsigned int v = (h32[i >> 1] >> ((i & 1) * 16)) & 0xFFFFu;
        hist[(size_t)g * npad2 + base + i] = (unsigned short)v;
    }
}

// K2: one thread PER NODE (parallelism!): single pass over g writing u16 prefix
// table off16[g][d], plus cnt[d] and dis[d].
__global__ void colscan_kernel(const unsigned short* __restrict__ hist,
                               unsigned short* __restrict__ off16,
                               int* __restrict__ cnt, float* __restrict__ dis,
                               int N, int npad2) {
    int d = blockIdx.x * blockDim.x + threadIdx.x;
    if (d >= N) return;
    int run = 0;
    for (int g = 0; g < G1; ++g) {
        off16[(size_t)g * npad2 + d] = (unsigned short)run;
        run += hist[(size_t)g * npad2 + d];
    }
    cnt[d] = run;
    dis[d] = rsqrtf((float)run + 1.0f);
}

// ==================== multi-block scan over cnt (exclusive) ====================
__global__ __launch_bounds__(256) void scan_block_sum(const int* __restrict__ cnt,
                                                      int* __restrict__ partial, int N) {
    __shared__ int s[256];
    int t = threadIdx.x;
    int base = blockIdx.x * 1024 + t * 4;
    int v = 0;
#pragma unroll
    for (int k = 0; k < 4; ++k) {
        int idx = base + k;
        if (idx < N) v += cnt[idx];
    }
    s[t] = v;
    __syncthreads();
    for (int off = 128; off > 0; off >>= 1) {
        if (t < off) s[t] += s[t + off];
        __syncthreads();
    }
    if (t == 0) partial[blockIdx.x] = s[0];
}

__global__ __launch_bounds__(64) void scan_partials(int* __restrict__ partial, int G) {
    int t = threadIdx.x;
    int o = (t < G) ? partial[t] : 0;
    int v = o;
#pragma unroll
    for (int off = 1; off < 64; off <<= 1) {
        int u = __shfl_up(v, off, 64);
        if (t >= off) v += u;
    }
    if (t < G) partial[t] = v - o;
}

__global__ __launch_bounds__(256) void scan_write(const int* __restrict__ cnt,
                                                  const int* __restrict__ partial,
                                                  int* __restrict__ cursor, int N) {
    __shared__ int s[256];
    int t = threadIdx.x;
    int base = blockIdx.x * 1024 + t * 4;
    int loc[4];
    int v = 0;
#pragma unroll
    for (int k = 0; k < 4; ++k) {
        int idx = base + k;
        loc[k] = (idx < N) ? cnt[idx] : 0;
        v += loc[k];
    }
    s[t] = v;
    __syncthreads();
    for (int off = 1; off < 256; off <<= 1) {
        int add = (t >= off) ? s[t - off] : 0;
        __syncthreads();
        s[t] += add;
        __syncthreads();
    }
    int run = partial[blockIdx.x] + s[t] - v;
#pragma unroll
    for (int k = 0; k < 4; ++k) {
        int idx = base + k;
        if (idx < N) {
            cursor[idx] = run;
            run += loc[k];
        }
    }
}

__global__ __launch_bounds__(1024) void scan_kernel(const int* __restrict__ cnt,
                                                    int* __restrict__ cursor, int N) {
    constexpr int T = 1024;
    __shared__ int sums[T];
    int t = threadIdx.x;
    int ch = (N + T - 1) / T;
    int base = t * ch;
    int local = 0;
    for (int k = 0; k < ch; ++k) {
        int idx = base + k;
        if (idx < N) local += cnt[idx];
    }
    sums[t] = local;
    __syncthreads();
    for (int off = 1; off < T; off <<= 1) {
        int add = (t >= off) ? sums[t - off] : 0;
        __syncthreads();
        sums[t] += add;
        __syncthreads();
    }
    int run = sums[t] - local;
    for (int k = 0; k < ch; ++k) {
        int idx = base + k;
        if (idx < N) {
            cursor[idx] = run;
            run += cnt[idx];
        }
    }
}

// K4: fill csr_src — u32 LDS counters preloaded with cursor+off16 give global pos directly.
__global__ __launch_bounds__(256) void fill2_kernel(const int* __restrict__ src,
                                                    const int* __restrict__ dst,
                                                    const int* __restrict__ cursor,
                                                    const unsigned short* __restrict__ off16,
                                                    int* __restrict__ csr_src,
                                                    int E, int chunk, int npad2) {
    __shared__ unsigned int c[RNODES];
    int g = blockIdx.x;
    int base = blockIdx.y * RNODES;
    for (int i = threadIdx.x; i < RNODES; i += 256)
        c[i] = (unsigned int)cursor[base + i] + (unsigned int)off16[(size_t)g * npad2 + base + i];
    __syncthreads();
    int e0 = g * chunk;
    int e1 = min(e0 + chunk, E);
    for (int e = e0 + threadIdx.x; e < e1; e += 256) {
        int d = dst[e] - base;
        if (d >= 0 && d < RNODES) {
            unsigned int pos = atomicAdd(&c[d], 1u);
            csr_src[pos] = src[e];
        }
    }
}

// ==================== fallback CSR build (device atomics) ====================
__global__ void degree_int_kernel(const int* __restrict__ dst, int* __restrict__ cnt, int E) {
    int i = blockIdx.x * blockDim.x + threadIdx.x;
    if (i < E) atomicAdd(&cnt[dst[i]], 1);
}

__global__ void dis_from_cnt_kernel(const int* __restrict__ cnt, float* __restrict__ dis, int N) {
    int i = blockIdx.x * blockDim.x + threadIdx.x;
    if (i < N) dis[i] = rsqrtf((float)cnt[i] + 1.0f);
}

__global__ void zero_int_kernel(int* __restrict__ p, int N) {
    int i = blockIdx.x * blockDim.x + threadIdx.x;
    if (i < N) p[i] = 0;
}

__global__ void fill_atomic_kernel(const int* __restrict__ src, const int* __restrict__ dst,
                                   int* __restrict__ cursor_mut, int* __restrict__ csr_src,
                                   int E) {
    int e = blockIdx.x * blockDim.x + threadIdx.x;
    if (e >= E) return;
    int pos = atomicAdd(&cursor_mut[dst[e]], 1);
    csr_src[pos] = src[e];
}

// ==================== cast+scale: Th[n][j] = half(x[n][j] * dis[n]) ====================
__global__ void cast_scale_kernel(const float* __restrict__ X, const float* __restrict__ dis,
                                  __half* __restrict__ Th, int N) {
    int i = blockIdx.x * blockDim.x + threadIdx.x;
    int n = i >> 3;
    if (n >= N) return;
    int c = (i & 7) * 8;
    float dn = dis[n];
    float4 a = *(const float4*)(X + (size_t)n * 64 + c);
    float4 b = *(const float4*)(X + (size_t)n * 64 + c + 4);
    __half2 h[4];
    h[0] = __floats2half2_rn(a.x * dn, a.y * dn);
    h[1] = __floats2half2_rn(a.z * dn, a.w * dn);
    h[2] = __floats2half2_rn(b.x * dn, b.y * dn);
    h[3] = __floats2half2_rn(b.z * dn, b.w * dn);
    *(float4*)(Th + (size_t)n * 64 + c) = *(float4*)h;
}

// ==================== tiled GEMM v2: k-unroll-4, float4 LDS X reads ====================
template <int K, int F, int RF, bool BIAS_RELU, bool OUT_HALF>
__global__ __launch_bounds__(256) void gemm_tiled(const float* __restrict__ X,
                                                  const float* __restrict__ W,
                                                  const float* __restrict__ bias,
                                                  const float* __restrict__ disscale,
                                                  void* __restrict__ outv, int N) {
    constexpr int TM = 64, RN = 4, XS = K + 4;
    static_assert(F == 16 * RF, "");
    __shared__ float Xs[TM * XS];
    __shared__ float Ws[K * F];

    const int n0 = blockIdx.x * TM;
    const int t = threadIdx.x;

    for (int i = t; i < (K * F) / 4; i += 256)
        ((float4*)Ws)[i] = ((const float4*)W)[i];
    for (int i = t; i < (TM * K) / 4; i += 256) {
        int row = i / (K / 4);
        int c4 = (i - row * (K / 4)) * 4;
        float4 v = make_float4(0.f, 0.f, 0.f, 0.f);
        if (n0 + row < N) v = *(const float4*)(X + (size_t)(n0 + row) * K + c4);
        *(float4*)(Xs + row * XS + c4) = v;
    }
    __syncthreads();

    const int tn = t >> 4;
    const int tf = t & 15;
    float acc[RN][RF] = {};
    for (int k0 = 0; k0 < K; k0 += 4) {
        float4 xv[RN];
#pragma unroll
        for (int i = 0; i < RN; ++i)
            xv[i] = *(const float4*)(Xs + (tn * RN + i) * XS + k0);
        float wv[4][RF];
#pragma unroll
        for (int j4 = 0; j4 < 4; ++j4)
#pragma unroll
            for (int j = 0; j < RF / 2; ++j) {
                float2 w2 = *(const float2*)(Ws + (k0 + j4) * F + tf * RF + 2 * j);
                wv[j4][2 * j] = w2.x;
                wv[j4][2 * j + 1] = w2.y;
            }
#pragma unroll
        for (int i = 0; i < RN; ++i) {
            const float xk[4] = {xv[i].x, xv[i].y, xv[i].z, xv[i].w};
#pragma unroll
            for (int j4 = 0; j4 < 4; ++j4)
#pragma unroll
                for (int j = 0; j < RF; ++j) acc[i][j] += xk[j4] * wv[j4][j];
        }
    }

    float breg[RF];
    if (BIAS_RELU) {
#pragma unroll
        for (int j = 0; j < RF; ++j) breg[j] = bias[tf * RF + j];
    }
#pragma unroll
    for (int i = 0; i < RN; ++i) {
        int n = n0 + tn * RN + i;
        if (n < N) {
            float v[RF];
#pragma unroll
            for (int j = 0; j < RF; ++j) {
                v[j] = acc[i][j];
                if (BIAS_RELU) v[j] = fmaxf(v[j] + breg[j], 0.f);
            }
            if (OUT_HALF) {
                float dn = disscale[n];
                __half* op = (__half*)outv + (size_t)n * F + tf * RF;
#pragma unroll
                for (int j = 0; j < RF / 2; ++j)
                    *(__half2*)(op + 2 * j) =
                        __floats2half2_rn(v[2 * j] * dn, v[2 * j + 1] * dn);
            } else {
                float* op = (float*)outv + (size_t)n * F + tf * RF;
#pragma unroll
                for (int j = 0; j < RF; ++j) op[j] = v[j];
            }
        }
    }
}

// ==================== CSR gather-aggregate, pre-scaled fp16 table ====================
// table rows pre-scaled by dis[src]; result = dn*(sum + self-row).
template <int MODE>
__global__ __launch_bounds__(256) void agg64h_kernel(const int* __restrict__ cursor,
                                                     const int* __restrict__ cnt,
                                                     const int* __restrict__ csr_src,
                                                     const float* __restrict__ dis,
                                                     const __half* __restrict__ Xh,
                                                     const float* __restrict__ b,
                                                     float* __restrict__ out, int N) {
    int i = blockIdx.x * 256 + threadIdx.x;
    int n = i >> 3;
    if (n >= N) return;
    int c = (i & 7) * 8;
    int beg = cursor[n];
    int end = beg + cnt[n];
    float a[8] = {};
    for (int j = beg; j < end; ++j) {
        int s = csr_src[j];
        float4 raw = *(const float4*)(Xh + (size_t)s * 64 + c);
        const __half2* hp = (const __half2*)&raw;
#pragma unroll
        for (int q = 0; q < 4; ++q) {
            float2 f = __half22float2(hp[q]);
            a[2 * q] += f.x;
            a[2 * q + 1] += f.y;
        }
    }
    {  // self row (pre-scaled by dis[n])
        float4 raw = *(const float4*)(Xh + (size_t)n * 64 + c);
        const __half2* hp = (const __half2*)&raw;
#pragma unroll
        for (int q = 0; q < 4; ++q) {
            float2 f = __half22float2(hp[q]);
            a[2 * q] += f.x;
            a[2 * q + 1] += f.y;
        }
    }
    float dn = dis[n];
    float r[8];
#pragma unroll
    for (int q = 0; q < 8; ++q) r[q] = a[q] * dn;
    if (MODE == 1) {
#pragma unroll
        for (int q = 0; q < 8; ++q) r[q] = 1.f / (1.f + expf(-(r[q] + b[c + q])));
    }
    *(float4*)(out + (size_t)n * 64 + c) = make_float4(r[0], r[1], r[2], r[3]);
    *(float4*)(out + (size_t)n * 64 + c + 4) = make_float4(r[4], r[5], r[6], r[7]);
}

// ============================ launch ============================
extern "C" void kernel_launch(void* const* d_in, const int* in_sizes, int n_in,
                              void* d_out, int out_size, void* d_ws, size_t ws_size,
                              hipStream_t stream) {
    const float* x  = (const float*)d_in[0];
    const int*   ei = (const int*)d_in[1];
    const float* W1 = (const float*)d_in[2];
    const float* b1 = (const float*)d_in[3];
    const float* W2 = (const float*)d_in[4];
    const float* b2 = (const float*)d_in[5];

    constexpr int LAT = 64, HID = 96, OUTF = 64;
    const int E = in_sizes[1] / 2;
    const int N = in_sizes[0] / LAT;
    const int* src = ei;
    const int* dst = ei + E;

    const int B = 256;
    auto blocks = [](long total, int b) { return (int)((total + b - 1) / b); };

    const int ranges = (N + RNODES - 1) / RNODES;
    const int npad2 = ranges * RNODES;
    const int chunk = (E + G1 - 1) / G1;

    // ---- workspace layout (node arrays sized to cover both N and npad2)
    long nmax = (npad2 > N) ? npad2 : N;
    size_t Na = (size_t)((nmax + 1023) / 1024) * 1024;
    size_t Epad = (size_t)((E + 3) / 4) * 4;
    int* cnt     = (int*)d_ws;               // Na
    int* cursor  = cnt + Na;                 // Na
    int* cursmut = cursor + Na;              // Na (fallback only)
    float* dis   = (float*)(cursmut + Na);   // Na
    int* partial = (int*)(dis + Na);         // 1024
    int* csr_src = partial + 1024;           // Epad
    char* region = (char*)(csr_src + Epad);
    // region phase A (build): hist u16 [G1*npad2] + off16 u16 [G1*npad2]
    unsigned short* hist  = (unsigned short*)region;
    unsigned short* off16 = hist + (size_t)G1 * npad2;
    // region phase B: Y fp32 [N*64] | H1 fp32 [N*96]; fp16 tables alias dead fp32 space
    float*  Y  = (float*)region;
    float*  H1 = Y + (size_t)N * 64;
    __half* Th = (__half*)H1;  // layer-1 table (dead before H1 written)

    size_t fixed = (4 * Na + 1024 + Epad) * sizeof(int);
    size_t regionA = (size_t)G1 * npad2 * 2 * sizeof(unsigned short);
    size_t regionB = ((size_t)N * 64 + (size_t)N * HID) * sizeof(float);
    size_t need = fixed + (regionA > regionB ? regionA : regionB);

    int Gn = blocks(N, 1024);
    bool fast = (ws_size >= need) && (chunk < 65536) && (ranges <= 8) && (Gn <= 64);

    if (fast) {
        dim3 g2(G1, ranges);
        histo_kernel<<<g2, 256, 0, stream>>>(dst, hist, E, chunk, npad2);
        colscan_kernel<<<blocks(N, B), B, 0, stream>>>(hist, off16, cnt, dis, N, npad2);
        scan_block_sum<<<Gn, 256, 0, stream>>>(cnt, partial, N);
        scan_partials<<<1, 64, 0, stream>>>(partial, Gn);
        scan_write<<<Gn, 256, 0, stream>>>(cnt, partial, cursor, N);
        fill2_kernel<<<g2, 256, 0, stream>>>(src, dst, cursor, off16, csr_src, E, chunk, npad2);
    } else {
        // fallback: device-atomic CSR build
        zero_int_kernel<<<blocks(N, B), B, 0, stream>>>(cnt, N);
        degree_int_kernel<<<blocks(E, B), B, 0, stream>>>(dst, cnt, E);
        dis_from_cnt_kernel<<<blocks(N, B), B, 0, stream>>>(cnt, dis, N);
        scan_kernel<<<1, 1024, 0, stream>>>(cnt, cursor, N);
        hipMemcpyAsync(cursmut, cursor, (size_t)N * sizeof(int), hipMemcpyDeviceToDevice, stream);
        fill_atomic_kernel<<<blocks(E, B), B, 0, stream>>>(src, dst, cursmut, csr_src, E);
    }

    // ---- layer 1: Th = half(x*dis); Y = dn*(sum Th); H1 = relu(Y@W1 + b1)
    cast_scale_kernel<<<blocks((long)N * 8, B), B, 0, stream>>>(x, dis, Th, N);
    agg64h_kernel<0><<<blocks((long)N * 8, B), B, 0, stream>>>(cursor, cnt, csr_src, dis, Th,
                                                               nullptr, Y, N);
    gemm_tiled<LAT, HID, 6, true, false>
        <<<blocks(N, 64), 256, 0, stream>>>(Y, W1, b1, nullptr, H1, N);

    // ---- layer 2: Th2 = half((H1@W2)*dis) (aliases Y); out = sigmoid(dn*sum + b2)
    gemm_tiled<HID, OUTF, 4, false, true>
        <<<blocks(N, 64), 256, 0, stream>>>(H1, W2, nullptr, dis, (void*)Y, N);
    agg64h_kernel<1><<<blocks((long)N * 8, B), B, 0, stream>>>(cursor, cnt, csr_src, dis,
                                                               (const __half*)Y, b2,
                                                               (float*)d_out, N);
}